// Round 1
// baseline (1138.428 us; speedup 1.0000x reference)
//
#include <hip/hip_runtime.h>

#define N_ROWS   131072
#define KCODES   128
#define DIM      510
#define DC       32          // d-chunk per LDS stage
#define RSTRIDE  36          // DC + 4 pad (144 B rows, 16B-aligned, lane-stride hits distinct bank quads)
#define BROWS    128         // rows per block
#define NCHUNK   16          // ceil(510/32)

// c_sq in fp64 (per-code errors shift dist per-code and can flip argmin; make them ~0)
__global__ __launch_bounds__(64) void csq_kernel(const float* __restrict__ cb,
                                                 float* __restrict__ csq) {
    int k = blockIdx.x;
    int l = threadIdx.x;
    double s = 0.0;
    for (int d = l; d < DIM; d += 64) {
        double v = (double)cb[k * DIM + d];
        s += v * v;
    }
    for (int m = 32; m > 0; m >>= 1) s += __shfl_down(s, m);
    if (l == 0) csq[k] = (float)s;
}

__global__ __launch_bounds__(256, 2) void vq_kernel(const float* __restrict__ z,
                                                    const float* __restrict__ cb,
                                                    const float* __restrict__ csq,
                                                    float* __restrict__ out) {
    __shared__ __align__(16) float zs[BROWS * RSTRIDE];
    __shared__ __align__(16) float cs[KCODES * RSTRIDE];
    __shared__ int kbest[BROWS];

    const int tid  = threadIdx.x;
    const int wave = tid >> 6;           // 0..3
    const int lane = tid & 63;
    const int lr   = lane >> 3;          // 0..7  (row group within wave)
    const int lc   = lane & 7;           // 0..7  (code group within wave)
    const long rowBase = (long)blockIdx.x * BROWS;

    // rows of this thread:  wave*32 + lr + 8*i   (i = 0..3)
    // codes of this thread: lc + 8*j             (j = 0..15, ascending k for tie-break)
    const int rbase = wave * 32 + lr;

    float acc[4][16];
    float zsq[4];
#pragma unroll
    for (int i = 0; i < 4; ++i) {
        zsq[i] = 0.f;
#pragma unroll
        for (int j = 0; j < 16; ++j) acc[i][j] = 0.f;
    }

    for (int ch = 0; ch < NCHUNK; ++ch) {
        const int d0 = ch * DC;
        __syncthreads();
        // stage z chunk: 128 rows x 32 d, coalesced, zero-pad tail
#pragma unroll
        for (int t = 0; t < 16; ++t) {
            int e = tid + 256 * t;
            int r = e >> 5;
            int d = e & 31;
            int gd = d0 + d;
            zs[r * RSTRIDE + d] = (gd < DIM) ? z[(rowBase + r) * DIM + gd] : 0.f;
        }
        // stage codebook chunk: 128 codes x 32 d
#pragma unroll
        for (int t = 0; t < 16; ++t) {
            int e = tid + 256 * t;
            int r = e >> 5;
            int d = e & 31;
            int gd = d0 + d;
            cs[r * RSTRIDE + d] = (gd < DIM) ? cb[r * DIM + gd] : 0.f;
        }
        __syncthreads();

#pragma unroll
        for (int dd = 0; dd < DC; dd += 4) {
            float4 zv[4];
#pragma unroll
            for (int i = 0; i < 4; ++i)
                zv[i] = *(const float4*)&zs[(rbase + 8 * i) * RSTRIDE + dd];
            // z_sq accumulated with the same chain structure as the dots
#pragma unroll
            for (int i = 0; i < 4; ++i) {
                zsq[i] = fmaf(zv[i].x, zv[i].x, zsq[i]);
                zsq[i] = fmaf(zv[i].y, zv[i].y, zsq[i]);
                zsq[i] = fmaf(zv[i].z, zv[i].z, zsq[i]);
                zsq[i] = fmaf(zv[i].w, zv[i].w, zsq[i]);
            }
#pragma unroll
            for (int j = 0; j < 16; ++j) {
                float4 cv = *(const float4*)&cs[(lc + 8 * j) * RSTRIDE + dd];
#pragma unroll
                for (int i = 0; i < 4; ++i) {
                    acc[i][j] = fmaf(zv[i].x, cv.x, acc[i][j]);
                    acc[i][j] = fmaf(zv[i].y, cv.y, acc[i][j]);
                    acc[i][j] = fmaf(zv[i].z, cv.z, acc[i][j]);
                    acc[i][j] = fmaf(zv[i].w, cv.w, acc[i][j]);
                }
            }
        }
    }

    // argmin epilogue — replicate np's rounding sequence:
    //   t = fp32(z_sq - 2*dot)  (2*dot exact);  dist = fp32(t + c_sq)
#pragma unroll
    for (int i = 0; i < 4; ++i) {
        float bd = 3.0e38f;
        int   bk = 0;
#pragma unroll
        for (int j = 0; j < 16; ++j) {
            int k = lc + 8 * j;
            float t    = zsq[i] - 2.0f * acc[i][j];
            float dist = t + csq[k];
            if (dist < bd) { bd = dist; bk = k; }   // strict <: first (lowest k) wins
        }
#pragma unroll
        for (int m = 1; m < 8; m <<= 1) {
            float od = __shfl_xor(bd, m);
            int   ok = __shfl_xor(bk, m);
            if (od < bd || (od == bd && ok < bk)) { bd = od; bk = ok; }
        }
        if (lc == 0) kbest[rbase + 8 * i] = bk;
    }
    __syncthreads();

    // gather: copy winning codebook rows to out (float2, rows are 8B-aligned)
    for (int r = wave; r < BROWS; r += 4) {
        int k = kbest[r];
        const float2* src = (const float2*)(cb + (long)k * DIM);
        float2* dst = (float2*)(out + (rowBase + r) * DIM);
        for (int d2 = lane; d2 < DIM / 2; d2 += 64) dst[d2] = src[d2];
    }
}

extern "C" void kernel_launch(void* const* d_in, const int* in_sizes, int n_in,
                              void* d_out, int out_size, void* d_ws, size_t ws_size,
                              hipStream_t stream) {
    const float* z  = (const float*)d_in[0];
    const float* cb = (const float*)d_in[1];
    float* out = (float*)d_out;
    float* csq = (float*)d_ws;   // 128 floats of scratch

    csq_kernel<<<KCODES, 64, 0, stream>>>(cb, csq);
    vq_kernel<<<N_ROWS / BROWS, 256, 0, stream>>>(z, cb, csq, out);
}